// Round 11
// baseline (83.919 us; speedup 1.0000x reference)
//
#include <hip/hip_runtime.h>
#include <hip/hip_bf16.h>

#define NN    64
#define CC    256
#define PP    16
#define FMAP  4096   // CC*PP
#define KCH   64     // k-chunks of 64 rows for the W_g matvec split
#define NBLK  512

// ---------------------------------------------------------------------------
// Single kernel, plain launch, manual device-scope barrier between phases.
// Phase A:
//   blocks [0,256):  mv role  — inline agg + W_g stream -> part (R7 code).
//   blocks [256,512): ub role — dual register-tiled GEMM -> U, Bm (R7 code).
// barrier (syncthreads -> threadfence -> atomic arrive/spin -> threadfence)
// Phase B:
//   blocks [0,256):  dist role -> edges (R7 code).
//   blocks [256,272): out role — kb-parallel reduce part + bias -> out.
// LDS: one 48 KB array; Phase-B scratch overlaid -> 3 blocks/CU, 512 resident.
// ---------------------------------------------------------------------------
__global__ __launch_bounds__(256) void k_all(const float* __restrict__ x,
                                             const float* __restrict__ We,
                                             const float* __restrict__ be,
                                             const float* __restrict__ Wg,
                                             const float* __restrict__ bg,
                                             float* __restrict__ U,
                                             float* __restrict__ Bm,
                                             float* __restrict__ part,
                                             float* __restrict__ out,
                                             float* __restrict__ edges,
                                             unsigned* __restrict__ cnt) {
    __shared__ float smem[3 * 4096];
    const int t = threadIdx.x;

    // ========================= PHASE A =========================
    if (blockIdx.x < 256) {
        // ---------------- mv role ----------------
        const int qx = blockIdx.x & 3;    // m quarter
        const int kb = blockIdx.x >> 2;   // k chunk (64 k's)

        {
            const int kl = t & 63, q = t >> 6;
            float s = 0.f;
            #pragma unroll
            for (int nn = 0; nn < 16; ++nn)
                s += x[(size_t)(q * 16 + nn) * FMAP + kb * 64 + kl];
            smem[q * 64 + kl] = s;
        }
        __syncthreads();
        if (t < 64)
            smem[256 + t] = (smem[t] + smem[64 + t] + smem[128 + t] + smem[192 + t])
                            * (1.0f / 64.0f);
        __syncthreads();
        const float* aggs = smem + 256;

        const int m0 = qx * 1024 + t * 4;
        float4 acc = make_float4(0.f, 0.f, 0.f, 0.f);
        #pragma unroll 4
        for (int r4 = 0; r4 < 16; ++r4) {
            const float4 av = *(const float4*)&aggs[r4 * 4];
            const int k = kb * 64 + r4 * 4;
            const float4 w0 = *(const float4*)&Wg[(size_t)(k    ) * FMAP + m0];
            const float4 w1 = *(const float4*)&Wg[(size_t)(k + 1) * FMAP + m0];
            const float4 w2 = *(const float4*)&Wg[(size_t)(k + 2) * FMAP + m0];
            const float4 w3 = *(const float4*)&Wg[(size_t)(k + 3) * FMAP + m0];
            acc.x = fmaf(av.x, w0.x, acc.x); acc.y = fmaf(av.x, w0.y, acc.y);
            acc.z = fmaf(av.x, w0.z, acc.z); acc.w = fmaf(av.x, w0.w, acc.w);
            acc.x = fmaf(av.y, w1.x, acc.x); acc.y = fmaf(av.y, w1.y, acc.y);
            acc.z = fmaf(av.y, w1.z, acc.z); acc.w = fmaf(av.y, w1.w, acc.w);
            acc.x = fmaf(av.z, w2.x, acc.x); acc.y = fmaf(av.z, w2.y, acc.y);
            acc.z = fmaf(av.z, w2.z, acc.z); acc.w = fmaf(av.z, w2.w, acc.w);
            acc.x = fmaf(av.w, w3.x, acc.x); acc.y = fmaf(av.w, w3.y, acc.y);
            acc.z = fmaf(av.w, w3.z, acc.z); acc.w = fmaf(av.w, w3.w, acc.w);
        }
        *(float4*)&part[(size_t)kb * FMAP + m0] = acc;
    } else {
        // ---------------- ub role ----------------
        const int b    = blockIdx.x - 256;
        const int o0   = (b & 7) * 32;
        const int col0 = (b >> 3) * 32;
        const int n0   = col0 >> 4;

        float* wts = smem;            // [kl][ol] : W1+W2
        float* wt2 = smem + 4096;     // [kl][ol] : W2
        float* xs  = smem + 8192;     // [kl][cl] : X

        const int kq  = t >> 6;
        const int pos = t & 63;
        const int og  = pos >> 3;
        const int cgi = pos & 7;
        const int wol = t >> 3, wseg = t & 7;

        float acc1[4][4] = {{0.f}}, acc2[4][4] = {{0.f}};

        for (int ch = 0; ch < 2; ++ch) {
            const int kb = ch * 128;
            if (ch) __syncthreads();

            {
                const float* wr = We + (size_t)(o0 + wol) * 512 + kb + wseg * 16;
                float w1v[16], w2v[16];
                #pragma unroll
                for (int q = 0; q < 16; q += 4) {
                    *(float4*)&w1v[q] = *(const float4*)(wr + q);
                    *(float4*)&w2v[q] = *(const float4*)(wr + 256 + q);
                }
                #pragma unroll
                for (int q = 0; q < 16; ++q) {
                    int kl = wseg * 16 + q;
                    wts[kl * 32 + wol] = w1v[q] + w2v[q];
                    wt2[kl * 32 + wol] = w2v[q];
                }
            }
            #pragma unroll
            for (int i = 0; i < 4; ++i) {
                int idx4 = t * 4 + i * 1024;
                int nl = idx4 >> 11, rem = idx4 & 2047;
                int kl = rem >> 4, p = rem & 15;
                float4 v = *(const float4*)&x[(size_t)(n0 + nl) * FMAP + (kb + kl) * PP + p];
                *(float4*)&xs[kl * 32 + nl * 16 + p] = v;
            }
            __syncthreads();

            const int kbase = kq * 32;
            #pragma unroll 8
            for (int kk = 0; kk < 32; ++kk) {
                int k = kbase + kk;
                const float4 a1 = *(const float4*)&wts[k * 32 + og * 4];
                const float4 a2 = *(const float4*)&wt2[k * 32 + og * 4];
                const float4 bx = *(const float4*)&xs [k * 32 + cgi * 4];
                const float av1[4] = {a1.x, a1.y, a1.z, a1.w};
                const float av2[4] = {a2.x, a2.y, a2.z, a2.w};
                const float bv [4] = {bx.x, bx.y, bx.z, bx.w};
                #pragma unroll
                for (int i2 = 0; i2 < 4; ++i2)
                    #pragma unroll
                    for (int j = 0; j < 4; ++j) {
                        acc1[i2][j] = fmaf(av1[i2], bv[j], acc1[i2][j]);
                        acc2[i2][j] = fmaf(av2[i2], bv[j], acc2[i2][j]);
                    }
            }
            __syncthreads();
        }

        float* red = smem;
        if (kq > 0) {
            float* dst = red + ((kq - 1) * 64 + pos) * 33;
            #pragma unroll
            for (int i2 = 0; i2 < 4; ++i2)
                #pragma unroll
                for (int j = 0; j < 4; ++j) {
                    dst[i2 * 4 + j]      = acc1[i2][j];
                    dst[16 + i2 * 4 + j] = acc2[i2][j];
                }
        }
        __syncthreads();
        if (kq == 0) {
            #pragma unroll
            for (int q = 0; q < 3; ++q) {
                const float* s = red + (q * 64 + pos) * 33;
                #pragma unroll
                for (int i2 = 0; i2 < 4; ++i2)
                    #pragma unroll
                    for (int j = 0; j < 4; ++j) {
                        acc1[i2][j] += s[i2 * 4 + j];
                        acc2[i2][j] += s[16 + i2 * 4 + j];
                    }
            }
            const int nl = cgi >> 2;
            const int p0 = (cgi * 4) & 15;
            const int n  = n0 + nl;
            #pragma unroll
            for (int i2 = 0; i2 < 4; ++i2) {
                const int o = o0 + og * 4 + i2;
                const float bias = be[o];
                const float4 xv = *(const float4*)&x[(size_t)n * FMAP + o * PP + p0];
                float4 uo, bo;
                uo.x = xv.x - acc1[i2][0] - bias;
                uo.y = xv.y - acc1[i2][1] - bias;
                uo.z = xv.z - acc1[i2][2] - bias;
                uo.w = xv.w - acc1[i2][3] - bias;
                bo.x = acc2[i2][0]; bo.y = acc2[i2][1];
                bo.z = acc2[i2][2]; bo.w = acc2[i2][3];
                *(float4*)&U [(size_t)n * FMAP + o * PP + p0] = uo;
                *(float4*)&Bm[(size_t)n * FMAP + o * PP + p0] = bo;
            }
        }
    }

    // ============== device-scope grid barrier ==============
    __syncthreads();                 // all waves' Phase-A stores drained (vmcnt 0)
    if (t == 0) {
        __threadfence();             // agent release: write-back L2
        __hip_atomic_fetch_add(cnt, 1u, __ATOMIC_RELAXED, __HIP_MEMORY_SCOPE_AGENT);
        while (__hip_atomic_load(cnt, __ATOMIC_RELAXED, __HIP_MEMORY_SCOPE_AGENT) < NBLK)
            __builtin_amdgcn_s_sleep(16);
        __threadfence();             // agent acquire: invalidate L1/L2
    }
    __syncthreads();

    // ========================= PHASE B =========================
    if (blockIdx.x < 256) {
        // ---------------- dist role ----------------
        const int i0 = (blockIdx.x >> 4) * 4;
        const int j0 = (blockIdx.x & 15) * 4;

        float acc[4][4] = {{0.f}};
        #pragma unroll
        for (int s = 0; s < 4; ++s) {
            const int m = s * 1024 + t * 4;
            float4 u[4], b[4];
            #pragma unroll
            for (int jl = 0; jl < 4; ++jl) u[jl] = *(const float4*)&U [(size_t)(j0 + jl) * FMAP + m];
            #pragma unroll
            for (int il = 0; il < 4; ++il) b[il] = *(const float4*)&Bm[(size_t)(i0 + il) * FMAP + m];
            #pragma unroll
            for (int il = 0; il < 4; ++il)
                #pragma unroll
                for (int jl = 0; jl < 4; ++jl) {
                    acc[il][jl] += fabsf(u[jl].x - b[il].x) + fabsf(u[jl].y - b[il].y)
                                 + fabsf(u[jl].z - b[il].z) + fabsf(u[jl].w - b[il].w);
                }
        }
        #pragma unroll
        for (int il = 0; il < 4; ++il)
            #pragma unroll
            for (int jl = 0; jl < 4; ++jl) {
                float v = acc[il][jl];
                #pragma unroll
                for (int msk = 1; msk < 64; msk <<= 1) v += __shfl_xor(v, msk, 64);
                acc[il][jl] = v;
            }
        float* wred = smem;              // overlay: 4*16 floats
        const int w = t >> 6;
        if ((t & 63) == 0) {
            #pragma unroll
            for (int il = 0; il < 4; ++il)
                #pragma unroll
                for (int jl = 0; jl < 4; ++jl) wred[w * 16 + il * 4 + jl] = acc[il][jl];
        }
        __syncthreads();
        if (t < 16) {
            const int il = t >> 2, jl = t & 3;
            const int i = i0 + il, j = j0 + jl;
            float v = wred[t] + wred[16 + t] + wred[32 + t] + wred[48 + t];
            edges[i * 64 + j] = (i == j) ? 1.0f : v;
        }
    } else if (blockIdx.x < 272) {
        // ---------------- out role ----------------
        const int mb = blockIdx.x - 256;      // 0..15
        const int kg = t >> 6;                // 4 kb-groups of 16 rows
        const int ml = t & 63;                // 64 float4 lanes
        const float* pp = part + (size_t)kg * 16 * FMAP + mb * 256 + ml * 4;
        float4 s = make_float4(0.f, 0.f, 0.f, 0.f);
        #pragma unroll
        for (int r = 0; r < 16; ++r) {
            const float4 v = *(const float4*)(pp + (size_t)r * FMAP);
            s.x += v.x; s.y += v.y; s.z += v.z; s.w += v.w;
        }
        float4* red4 = (float4*)smem;         // overlay: 4*64 float4 (4 KB)
        float*  rst  = smem + 2048;           // overlay: 256 floats
        red4[kg * 64 + ml] = s;
        __syncthreads();
        if (t < 64) {
            const float4 a = red4[t], b = red4[64 + t], c = red4[128 + t], d = red4[192 + t];
            const float4 bgv = *(const float4*)&bg[mb * 256 + t * 4];
            float4 r;
            r.x = a.x + b.x + c.x + d.x + bgv.x;
            r.y = a.y + b.y + c.y + d.y + bgv.y;
            r.z = a.z + b.z + c.z + d.z + bgv.z;
            r.w = a.w + b.w + c.w + d.w + bgv.w;
            *(float4*)&rst[t * 4] = r;
        }
        __syncthreads();
        const int row0 = t >> 6;    // 0..3
        const int c4   = t & 63;
        const float4 v = *(const float4*)&rst[c4 * 4];
        #pragma unroll
        for (int p = 0; p < 16; ++p) {
            const int n = p * 4 + row0;
            *(float4*)&out[(size_t)n * FMAP + mb * 256 + c4 * 4] = v;
        }
    }
}

extern "C" void kernel_launch(void* const* d_in, const int* in_sizes, int n_in,
                              void* d_out, int out_size, void* d_ws, size_t ws_size,
                              hipStream_t stream) {
    const float* x  = (const float*)d_in[0];   // (64,1,256,4,4)
    const float* We = (const float*)d_in[1];   // (256,512)
    const float* be = (const float*)d_in[2];   // (256,)
    const float* Wg = (const float*)d_in[3];   // (4096,4096)
    const float* bg = (const float*)d_in[4];   // (4096,)
    float* out   = (float*)d_out;
    float* edges = out + (size_t)NN * FMAP;

    unsigned* cnt = (unsigned*)d_ws;               // barrier counter (zeroed below)
    float* fws  = (float*)((char*)d_ws + 256);
    float* U    = fws;                             // 262144 floats (1 MB)
    float* Bm   = U + (size_t)NN * FMAP;           // 262144 floats (1 MB)
    float* part = Bm + (size_t)NN * FMAP;          // KCH*FMAP = 262144 floats (1 MB)

    hipMemsetAsync(cnt, 0, 256, stream);           // captured as a memset node
    k_all<<<dim3(NBLK), 256, 0, stream>>>(x, We, be, Wg, bg,
                                          U, Bm, part, out, edges, cnt);
}

// Round 12
// 67.966 us; speedup vs baseline: 1.2347x; 1.2347x over previous
//
#include <hip/hip_runtime.h>
#include <hip/hip_bf16.h>

#define NN    64
#define CC    256
#define PP    16
#define FMAP  4096   // CC*PP
#define KCH   64     // k-chunks of 64 rows for the W_g matvec split
#define NBLK  512

// ---------------------------------------------------------------------------
// Single fused kernel, plain launch. Phases as R11 (mv+ub || barrier || dist+out).
// Barrier v2: relaxed-atomic arrive/spin + ONE buffer_wbl2 per XCD (elected via
// HW_REG_XCC_ID). No per-block threadfence, no L2 invalidate (no stale clean
// copies exist: U/Bm/part are never read in Phase A and kernel-start inv'd).
// ---------------------------------------------------------------------------
__global__ __launch_bounds__(256) void k_all(const float* __restrict__ x,
                                             const float* __restrict__ We,
                                             const float* __restrict__ be,
                                             const float* __restrict__ Wg,
                                             const float* __restrict__ bg,
                                             float* __restrict__ U,
                                             float* __restrict__ Bm,
                                             float* __restrict__ part,
                                             float* __restrict__ out,
                                             float* __restrict__ edges,
                                             unsigned* __restrict__ sync) {
    __shared__ float smem[3 * 4096];
    const int t = threadIdx.x;

    // ========================= PHASE A =========================
    if (blockIdx.x < 256) {
        // ---------------- mv role ----------------
        const int qx = blockIdx.x & 3;    // m quarter
        const int kb = blockIdx.x >> 2;   // k chunk (64 k's)

        {
            const int kl = t & 63, q = t >> 6;
            float s = 0.f;
            #pragma unroll
            for (int nn = 0; nn < 16; ++nn)
                s += x[(size_t)(q * 16 + nn) * FMAP + kb * 64 + kl];
            smem[q * 64 + kl] = s;
        }
        __syncthreads();
        if (t < 64)
            smem[256 + t] = (smem[t] + smem[64 + t] + smem[128 + t] + smem[192 + t])
                            * (1.0f / 64.0f);
        __syncthreads();
        const float* aggs = smem + 256;

        const int m0 = qx * 1024 + t * 4;
        float4 acc = make_float4(0.f, 0.f, 0.f, 0.f);
        #pragma unroll 4
        for (int r4 = 0; r4 < 16; ++r4) {
            const float4 av = *(const float4*)&aggs[r4 * 4];
            const int k = kb * 64 + r4 * 4;
            const float4 w0 = *(const float4*)&Wg[(size_t)(k    ) * FMAP + m0];
            const float4 w1 = *(const float4*)&Wg[(size_t)(k + 1) * FMAP + m0];
            const float4 w2 = *(const float4*)&Wg[(size_t)(k + 2) * FMAP + m0];
            const float4 w3 = *(const float4*)&Wg[(size_t)(k + 3) * FMAP + m0];
            acc.x = fmaf(av.x, w0.x, acc.x); acc.y = fmaf(av.x, w0.y, acc.y);
            acc.z = fmaf(av.x, w0.z, acc.z); acc.w = fmaf(av.x, w0.w, acc.w);
            acc.x = fmaf(av.y, w1.x, acc.x); acc.y = fmaf(av.y, w1.y, acc.y);
            acc.z = fmaf(av.y, w1.z, acc.z); acc.w = fmaf(av.y, w1.w, acc.w);
            acc.x = fmaf(av.z, w2.x, acc.x); acc.y = fmaf(av.z, w2.y, acc.y);
            acc.z = fmaf(av.z, w2.z, acc.z); acc.w = fmaf(av.z, w2.w, acc.w);
            acc.x = fmaf(av.w, w3.x, acc.x); acc.y = fmaf(av.w, w3.y, acc.y);
            acc.z = fmaf(av.w, w3.z, acc.z); acc.w = fmaf(av.w, w3.w, acc.w);
        }
        *(float4*)&part[(size_t)kb * FMAP + m0] = acc;
    } else {
        // ---------------- ub role ----------------
        const int b    = blockIdx.x - 256;
        const int o0   = (b & 7) * 32;
        const int col0 = (b >> 3) * 32;
        const int n0   = col0 >> 4;

        float* wts = smem;            // [kl][ol] : W1+W2
        float* wt2 = smem + 4096;     // [kl][ol] : W2
        float* xs  = smem + 8192;     // [kl][cl] : X

        const int kq  = t >> 6;
        const int pos = t & 63;
        const int og  = pos >> 3;
        const int cgi = pos & 7;
        const int wol = t >> 3, wseg = t & 7;

        float acc1[4][4] = {{0.f}}, acc2[4][4] = {{0.f}};

        for (int ch = 0; ch < 2; ++ch) {
            const int kb = ch * 128;
            if (ch) __syncthreads();

            {
                const float* wr = We + (size_t)(o0 + wol) * 512 + kb + wseg * 16;
                float w1v[16], w2v[16];
                #pragma unroll
                for (int q = 0; q < 16; q += 4) {
                    *(float4*)&w1v[q] = *(const float4*)(wr + q);
                    *(float4*)&w2v[q] = *(const float4*)(wr + 256 + q);
                }
                #pragma unroll
                for (int q = 0; q < 16; ++q) {
                    int kl = wseg * 16 + q;
                    wts[kl * 32 + wol] = w1v[q] + w2v[q];
                    wt2[kl * 32 + wol] = w2v[q];
                }
            }
            #pragma unroll
            for (int i = 0; i < 4; ++i) {
                int idx4 = t * 4 + i * 1024;
                int nl = idx4 >> 11, rem = idx4 & 2047;
                int kl = rem >> 4, p = rem & 15;
                float4 v = *(const float4*)&x[(size_t)(n0 + nl) * FMAP + (kb + kl) * PP + p];
                *(float4*)&xs[kl * 32 + nl * 16 + p] = v;
            }
            __syncthreads();

            const int kbase = kq * 32;
            #pragma unroll 8
            for (int kk = 0; kk < 32; ++kk) {
                int k = kbase + kk;
                const float4 a1 = *(const float4*)&wts[k * 32 + og * 4];
                const float4 a2 = *(const float4*)&wt2[k * 32 + og * 4];
                const float4 bx = *(const float4*)&xs [k * 32 + cgi * 4];
                const float av1[4] = {a1.x, a1.y, a1.z, a1.w};
                const float av2[4] = {a2.x, a2.y, a2.z, a2.w};
                const float bv [4] = {bx.x, bx.y, bx.z, bx.w};
                #pragma unroll
                for (int i2 = 0; i2 < 4; ++i2)
                    #pragma unroll
                    for (int j = 0; j < 4; ++j) {
                        acc1[i2][j] = fmaf(av1[i2], bv[j], acc1[i2][j]);
                        acc2[i2][j] = fmaf(av2[i2], bv[j], acc2[i2][j]);
                    }
            }
            __syncthreads();
        }

        float* red = smem;
        if (kq > 0) {
            float* dst = red + ((kq - 1) * 64 + pos) * 33;
            #pragma unroll
            for (int i2 = 0; i2 < 4; ++i2)
                #pragma unroll
                for (int j = 0; j < 4; ++j) {
                    dst[i2 * 4 + j]      = acc1[i2][j];
                    dst[16 + i2 * 4 + j] = acc2[i2][j];
                }
        }
        __syncthreads();
        if (kq == 0) {
            #pragma unroll
            for (int q = 0; q < 3; ++q) {
                const float* s = red + (q * 64 + pos) * 33;
                #pragma unroll
                for (int i2 = 0; i2 < 4; ++i2)
                    #pragma unroll
                    for (int j = 0; j < 4; ++j) {
                        acc1[i2][j] += s[i2 * 4 + j];
                        acc2[i2][j] += s[16 + i2 * 4 + j];
                    }
            }
            const int nl = cgi >> 2;
            const int p0 = (cgi * 4) & 15;
            const int n  = n0 + nl;
            #pragma unroll
            for (int i2 = 0; i2 < 4; ++i2) {
                const int o = o0 + og * 4 + i2;
                const float bias = be[o];
                const float4 xv = *(const float4*)&x[(size_t)n * FMAP + o * PP + p0];
                float4 uo, bo;
                uo.x = xv.x - acc1[i2][0] - bias;
                uo.y = xv.y - acc1[i2][1] - bias;
                uo.z = xv.z - acc1[i2][2] - bias;
                uo.w = xv.w - acc1[i2][3] - bias;
                bo.x = acc2[i2][0]; bo.y = acc2[i2][1];
                bo.z = acc2[i2][2]; bo.w = acc2[i2][3];
                *(float4*)&U [(size_t)n * FMAP + o * PP + p0] = uo;
                *(float4*)&Bm[(size_t)n * FMAP + o * PP + p0] = bo;
            }
        }
    }

    // ============== cheap device-scope grid barrier ==============
    // sync[0]=arrive1, sync[1]=arrive2, sync[8..15]=per-XCD flush flags.
    __syncthreads();                 // all waves' Phase-A stores are in L2 (vmcnt 0)
    if (t == 0) {
        __hip_atomic_fetch_add(&sync[0], 1u, __ATOMIC_RELAXED, __HIP_MEMORY_SCOPE_AGENT);
        while (__hip_atomic_load(&sync[0], __ATOMIC_RELAXED, __HIP_MEMORY_SCOPE_AGENT) < NBLK)
            __builtin_amdgcn_s_sleep(8);
        asm volatile("" ::: "memory");
        // elect one flusher per XCD; winner writes back its XCD's dirty L2
        unsigned xcd;
        asm volatile("s_getreg_b32 %0, hwreg(HW_REG_XCC_ID)" : "=s"(xcd));
        unsigned old = __hip_atomic_fetch_or(&sync[8 + (xcd & 7)], 1u,
                                             __ATOMIC_RELAXED, __HIP_MEMORY_SCOPE_AGENT);
        if (old == 0) {
            asm volatile("buffer_wbl2 sc1\n\t"
                         "s_waitcnt vmcnt(0)" ::: "memory");
        }
        __hip_atomic_fetch_add(&sync[1], 1u, __ATOMIC_RELAXED, __HIP_MEMORY_SCOPE_AGENT);
        while (__hip_atomic_load(&sync[1], __ATOMIC_RELAXED, __HIP_MEMORY_SCOPE_AGENT) < NBLK)
            __builtin_amdgcn_s_sleep(8);
        asm volatile("" ::: "memory");
    }
    __syncthreads();

    // ========================= PHASE B =========================
    if (blockIdx.x < 256) {
        // ---------------- dist role ----------------
        const int i0 = (blockIdx.x >> 4) * 4;
        const int j0 = (blockIdx.x & 15) * 4;

        float acc[4][4] = {{0.f}};
        #pragma unroll
        for (int s = 0; s < 4; ++s) {
            const int m = s * 1024 + t * 4;
            float4 u[4], b[4];
            #pragma unroll
            for (int jl = 0; jl < 4; ++jl) u[jl] = *(const float4*)&U [(size_t)(j0 + jl) * FMAP + m];
            #pragma unroll
            for (int il = 0; il < 4; ++il) b[il] = *(const float4*)&Bm[(size_t)(i0 + il) * FMAP + m];
            #pragma unroll
            for (int il = 0; il < 4; ++il)
                #pragma unroll
                for (int jl = 0; jl < 4; ++jl) {
                    acc[il][jl] += fabsf(u[jl].x - b[il].x) + fabsf(u[jl].y - b[il].y)
                                 + fabsf(u[jl].z - b[il].z) + fabsf(u[jl].w - b[il].w);
                }
        }
        #pragma unroll
        for (int il = 0; il < 4; ++il)
            #pragma unroll
            for (int jl = 0; jl < 4; ++jl) {
                float v = acc[il][jl];
                #pragma unroll
                for (int msk = 1; msk < 64; msk <<= 1) v += __shfl_xor(v, msk, 64);
                acc[il][jl] = v;
            }
        float* wred = smem;              // overlay: 4*16 floats
        const int w = t >> 6;
        if ((t & 63) == 0) {
            #pragma unroll
            for (int il = 0; il < 4; ++il)
                #pragma unroll
                for (int jl = 0; jl < 4; ++jl) wred[w * 16 + il * 4 + jl] = acc[il][jl];
        }
        __syncthreads();
        if (t < 16) {
            const int il = t >> 2, jl = t & 3;
            const int i = i0 + il, j = j0 + jl;
            float v = wred[t] + wred[16 + t] + wred[32 + t] + wred[48 + t];
            edges[i * 64 + j] = (i == j) ? 1.0f : v;
        }
    } else if (blockIdx.x < 272) {
        // ---------------- out role ----------------
        const int mb = blockIdx.x - 256;      // 0..15
        const int kg = t >> 6;                // 4 kb-groups of 16 rows
        const int ml = t & 63;                // 64 float4 lanes
        const float* pp = part + (size_t)kg * 16 * FMAP + mb * 256 + ml * 4;
        float4 s = make_float4(0.f, 0.f, 0.f, 0.f);
        #pragma unroll
        for (int r = 0; r < 16; ++r) {
            const float4 v = *(const float4*)(pp + (size_t)r * FMAP);
            s.x += v.x; s.y += v.y; s.z += v.z; s.w += v.w;
        }
        float4* red4 = (float4*)smem;         // overlay: 4*64 float4 (4 KB)
        float*  rst  = smem + 2048;           // overlay: 256 floats
        red4[kg * 64 + ml] = s;
        __syncthreads();
        if (t < 64) {
            const float4 a = red4[t], b = red4[64 + t], c = red4[128 + t], d = red4[192 + t];
            const float4 bgv = *(const float4*)&bg[mb * 256 + t * 4];
            float4 r;
            r.x = a.x + b.x + c.x + d.x + bgv.x;
            r.y = a.y + b.y + c.y + d.y + bgv.y;
            r.z = a.z + b.z + c.z + d.z + bgv.z;
            r.w = a.w + b.w + c.w + d.w + bgv.w;
            *(float4*)&rst[t * 4] = r;
        }
        __syncthreads();
        const int row0 = t >> 6;    // 0..3
        const int c4   = t & 63;
        const float4 v = *(const float4*)&rst[c4 * 4];
        #pragma unroll
        for (int p = 0; p < 16; ++p) {
            const int n = p * 4 + row0;
            *(float4*)&out[(size_t)n * FMAP + mb * 256 + c4 * 4] = v;
        }
    }
}

extern "C" void kernel_launch(void* const* d_in, const int* in_sizes, int n_in,
                              void* d_out, int out_size, void* d_ws, size_t ws_size,
                              hipStream_t stream) {
    const float* x  = (const float*)d_in[0];   // (64,1,256,4,4)
    const float* We = (const float*)d_in[1];   // (256,512)
    const float* be = (const float*)d_in[2];   // (256,)
    const float* Wg = (const float*)d_in[3];   // (4096,4096)
    const float* bg = (const float*)d_in[4];   // (4096,)
    float* out   = (float*)d_out;
    float* edges = out + (size_t)NN * FMAP;

    unsigned* syncv = (unsigned*)d_ws;             // barrier counters + flags
    float* fws  = (float*)((char*)d_ws + 256);
    float* U    = fws;                             // 262144 floats (1 MB)
    float* Bm   = U + (size_t)NN * FMAP;           // 262144 floats (1 MB)
    float* part = Bm + (size_t)NN * FMAP;          // KCH*FMAP = 262144 floats (1 MB)

    hipMemsetAsync(syncv, 0, 256, stream);         // zero counters each replay
    k_all<<<dim3(NBLK), 256, 0, stream>>>(x, We, be, Wg, bg,
                                          U, Bm, part, out, edges, syncv);
}

// Round 13
// 35.945 us; speedup vs baseline: 2.3347x; 1.8909x over previous
//
#include <hip/hip_runtime.h>
#include <hip/hip_bf16.h>

#define NN    64
#define CC    256
#define PP    16
#define FMAP  4096   // CC*PP
#define KCH   64     // k-chunks of 64 rows for the W_g matvec split
#define NBLK  512

// ---------------------------------------------------------------------------
// Single fused kernel, plain launch. Phases as R12 (mv+ub || barrier || dist+out).
// Barrier v3 (hierarchical, low-contention):
//   round 1: arrive on 16 spread cachelines (32 blocks each) -> masters
//            aggregate -> release flag 1 (read-only spin).
//   round 2: per-XCD fetch_or election; winner buffer_wbl2 sc1 + vmcnt(0).
//   round 3: second 16-line arrive -> release flag 2 (ensures flushes done).
// ---------------------------------------------------------------------------
__global__ __launch_bounds__(256) void k_all(const float* __restrict__ x,
                                             const float* __restrict__ We,
                                             const float* __restrict__ be,
                                             const float* __restrict__ Wg,
                                             const float* __restrict__ bg,
                                             float* __restrict__ U,
                                             float* __restrict__ Bm,
                                             float* __restrict__ part,
                                             float* __restrict__ out,
                                             float* __restrict__ edges,
                                             unsigned* __restrict__ sync) {
    __shared__ float smem[3 * 4096];
    const int t = threadIdx.x;

    // ========================= PHASE A =========================
    if (blockIdx.x < 256) {
        // ---------------- mv role ----------------
        const int qx = blockIdx.x & 3;    // m quarter
        const int kb = blockIdx.x >> 2;   // k chunk (64 k's)

        {
            const int kl = t & 63, q = t >> 6;
            float s = 0.f;
            #pragma unroll
            for (int nn = 0; nn < 16; ++nn)
                s += x[(size_t)(q * 16 + nn) * FMAP + kb * 64 + kl];
            smem[q * 64 + kl] = s;
        }
        __syncthreads();
        if (t < 64)
            smem[256 + t] = (smem[t] + smem[64 + t] + smem[128 + t] + smem[192 + t])
                            * (1.0f / 64.0f);
        __syncthreads();
        const float* aggs = smem + 256;

        const int m0 = qx * 1024 + t * 4;
        float4 acc = make_float4(0.f, 0.f, 0.f, 0.f);
        #pragma unroll 4
        for (int r4 = 0; r4 < 16; ++r4) {
            const float4 av = *(const float4*)&aggs[r4 * 4];
            const int k = kb * 64 + r4 * 4;
            const float4 w0 = *(const float4*)&Wg[(size_t)(k    ) * FMAP + m0];
            const float4 w1 = *(const float4*)&Wg[(size_t)(k + 1) * FMAP + m0];
            const float4 w2 = *(const float4*)&Wg[(size_t)(k + 2) * FMAP + m0];
            const float4 w3 = *(const float4*)&Wg[(size_t)(k + 3) * FMAP + m0];
            acc.x = fmaf(av.x, w0.x, acc.x); acc.y = fmaf(av.x, w0.y, acc.y);
            acc.z = fmaf(av.x, w0.z, acc.z); acc.w = fmaf(av.x, w0.w, acc.w);
            acc.x = fmaf(av.y, w1.x, acc.x); acc.y = fmaf(av.y, w1.y, acc.y);
            acc.z = fmaf(av.y, w1.z, acc.z); acc.w = fmaf(av.y, w1.w, acc.w);
            acc.x = fmaf(av.z, w2.x, acc.x); acc.y = fmaf(av.z, w2.y, acc.y);
            acc.z = fmaf(av.z, w2.z, acc.z); acc.w = fmaf(av.z, w2.w, acc.w);
            acc.x = fmaf(av.w, w3.x, acc.x); acc.y = fmaf(av.w, w3.y, acc.y);
            acc.z = fmaf(av.w, w3.z, acc.z); acc.w = fmaf(av.w, w3.w, acc.w);
        }
        *(float4*)&part[(size_t)kb * FMAP + m0] = acc;
    } else {
        // ---------------- ub role ----------------
        const int b    = blockIdx.x - 256;
        const int o0   = (b & 7) * 32;
        const int col0 = (b >> 3) * 32;
        const int n0   = col0 >> 4;

        float* wts = smem;            // [kl][ol] : W1+W2
        float* wt2 = smem + 4096;     // [kl][ol] : W2
        float* xs  = smem + 8192;     // [kl][cl] : X

        const int kq  = t >> 6;
        const int pos = t & 63;
        const int og  = pos >> 3;
        const int cgi = pos & 7;
        const int wol = t >> 3, wseg = t & 7;

        float acc1[4][4] = {{0.f}}, acc2[4][4] = {{0.f}};

        for (int ch = 0; ch < 2; ++ch) {
            const int kb = ch * 128;
            if (ch) __syncthreads();

            {
                const float* wr = We + (size_t)(o0 + wol) * 512 + kb + wseg * 16;
                float w1v[16], w2v[16];
                #pragma unroll
                for (int q = 0; q < 16; q += 4) {
                    *(float4*)&w1v[q] = *(const float4*)(wr + q);
                    *(float4*)&w2v[q] = *(const float4*)(wr + 256 + q);
                }
                #pragma unroll
                for (int q = 0; q < 16; ++q) {
                    int kl = wseg * 16 + q;
                    wts[kl * 32 + wol] = w1v[q] + w2v[q];
                    wt2[kl * 32 + wol] = w2v[q];
                }
            }
            #pragma unroll
            for (int i = 0; i < 4; ++i) {
                int idx4 = t * 4 + i * 1024;
                int nl = idx4 >> 11, rem = idx4 & 2047;
                int kl = rem >> 4, p = rem & 15;
                float4 v = *(const float4*)&x[(size_t)(n0 + nl) * FMAP + (kb + kl) * PP + p];
                *(float4*)&xs[kl * 32 + nl * 16 + p] = v;
            }
            __syncthreads();

            const int kbase = kq * 32;
            #pragma unroll 8
            for (int kk = 0; kk < 32; ++kk) {
                int k = kbase + kk;
                const float4 a1 = *(const float4*)&wts[k * 32 + og * 4];
                const float4 a2 = *(const float4*)&wt2[k * 32 + og * 4];
                const float4 bx = *(const float4*)&xs [k * 32 + cgi * 4];
                const float av1[4] = {a1.x, a1.y, a1.z, a1.w};
                const float av2[4] = {a2.x, a2.y, a2.z, a2.w};
                const float bv [4] = {bx.x, bx.y, bx.z, bx.w};
                #pragma unroll
                for (int i2 = 0; i2 < 4; ++i2)
                    #pragma unroll
                    for (int j = 0; j < 4; ++j) {
                        acc1[i2][j] = fmaf(av1[i2], bv[j], acc1[i2][j]);
                        acc2[i2][j] = fmaf(av2[i2], bv[j], acc2[i2][j]);
                    }
            }
            __syncthreads();
        }

        float* red = smem;
        if (kq > 0) {
            float* dst = red + ((kq - 1) * 64 + pos) * 33;
            #pragma unroll
            for (int i2 = 0; i2 < 4; ++i2)
                #pragma unroll
                for (int j = 0; j < 4; ++j) {
                    dst[i2 * 4 + j]      = acc1[i2][j];
                    dst[16 + i2 * 4 + j] = acc2[i2][j];
                }
        }
        __syncthreads();
        if (kq == 0) {
            #pragma unroll
            for (int q = 0; q < 3; ++q) {
                const float* s = red + (q * 64 + pos) * 33;
                #pragma unroll
                for (int i2 = 0; i2 < 4; ++i2)
                    #pragma unroll
                    for (int j = 0; j < 4; ++j) {
                        acc1[i2][j] += s[i2 * 4 + j];
                        acc2[i2][j] += s[16 + i2 * 4 + j];
                    }
            }
            const int nl = cgi >> 2;
            const int p0 = (cgi * 4) & 15;
            const int n  = n0 + nl;
            #pragma unroll
            for (int i2 = 0; i2 < 4; ++i2) {
                const int o = o0 + og * 4 + i2;
                const float bias = be[o];
                const float4 xv = *(const float4*)&x[(size_t)n * FMAP + o * PP + p0];
                float4 uo, bo;
                uo.x = xv.x - acc1[i2][0] - bias;
                uo.y = xv.y - acc1[i2][1] - bias;
                uo.z = xv.z - acc1[i2][2] - bias;
                uo.w = xv.w - acc1[i2][3] - bias;
                bo.x = acc2[i2][0]; bo.y = acc2[i2][1];
                bo.z = acc2[i2][2]; bo.w = acc2[i2][3];
                *(float4*)&U [(size_t)n * FMAP + o * PP + p0] = uo;
                *(float4*)&Bm[(size_t)n * FMAP + o * PP + p0] = bo;
            }
        }
    }

    // ============== hierarchical device-scope grid barrier ==============
    // layout (dwords): grp1[s]=sync[s*32] s<16; g1=sync[512]; rel1=sync[544];
    // xcdflag[x]=sync[576+x*32] x<8; grp2[s]=sync[832+s*32]; g2=sync[1344];
    // rel2=sync[1376].
    __syncthreads();                 // Phase-A stores drained to L2 (vmcnt 0)
    if (t == 0) {
        const int slot = (blockIdx.x & 15) * 32;
        // round 1: low-contention arrive
        if (__hip_atomic_fetch_add(&sync[slot], 1u, __ATOMIC_RELAXED,
                                   __HIP_MEMORY_SCOPE_AGENT) == 31u) {
            if (__hip_atomic_fetch_add(&sync[512], 1u, __ATOMIC_RELAXED,
                                       __HIP_MEMORY_SCOPE_AGENT) == 15u)
                __hip_atomic_store(&sync[544], 1u, __ATOMIC_RELAXED,
                                   __HIP_MEMORY_SCOPE_AGENT);
        }
        while (!__hip_atomic_load(&sync[544], __ATOMIC_RELAXED,
                                  __HIP_MEMORY_SCOPE_AGENT))
            __builtin_amdgcn_s_sleep(16);
        asm volatile("" ::: "memory");
        // round 2: one L2 writeback per XCD
        unsigned xcd;
        asm volatile("s_getreg_b32 %0, hwreg(HW_REG_XCC_ID)" : "=s"(xcd));
        if (__hip_atomic_fetch_or(&sync[576 + (xcd & 7) * 32], 1u, __ATOMIC_RELAXED,
                                  __HIP_MEMORY_SCOPE_AGENT) == 0u) {
            asm volatile("buffer_wbl2 sc1\n\t"
                         "s_waitcnt vmcnt(0)" ::: "memory");
        }
        // round 3: arrive again -> all flushes complete
        if (__hip_atomic_fetch_add(&sync[832 + slot], 1u, __ATOMIC_RELAXED,
                                   __HIP_MEMORY_SCOPE_AGENT) == 31u) {
            if (__hip_atomic_fetch_add(&sync[1344], 1u, __ATOMIC_RELAXED,
                                       __HIP_MEMORY_SCOPE_AGENT) == 15u)
                __hip_atomic_store(&sync[1376], 1u, __ATOMIC_RELAXED,
                                   __HIP_MEMORY_SCOPE_AGENT);
        }
        while (!__hip_atomic_load(&sync[1376], __ATOMIC_RELAXED,
                                  __HIP_MEMORY_SCOPE_AGENT))
            __builtin_amdgcn_s_sleep(16);
        asm volatile("" ::: "memory");
    }
    __syncthreads();

    // ========================= PHASE B =========================
    if (blockIdx.x < 256) {
        // ---------------- dist role ----------------
        const int i0 = (blockIdx.x >> 4) * 4;
        const int j0 = (blockIdx.x & 15) * 4;

        float acc[4][4] = {{0.f}};
        #pragma unroll
        for (int s = 0; s < 4; ++s) {
            const int m = s * 1024 + t * 4;
            float4 u[4], b[4];
            #pragma unroll
            for (int jl = 0; jl < 4; ++jl) u[jl] = *(const float4*)&U [(size_t)(j0 + jl) * FMAP + m];
            #pragma unroll
            for (int il = 0; il < 4; ++il) b[il] = *(const float4*)&Bm[(size_t)(i0 + il) * FMAP + m];
            #pragma unroll
            for (int il = 0; il < 4; ++il)
                #pragma unroll
                for (int jl = 0; jl < 4; ++jl) {
                    acc[il][jl] += fabsf(u[jl].x - b[il].x) + fabsf(u[jl].y - b[il].y)
                                 + fabsf(u[jl].z - b[il].z) + fabsf(u[jl].w - b[il].w);
                }
        }
        #pragma unroll
        for (int il = 0; il < 4; ++il)
            #pragma unroll
            for (int jl = 0; jl < 4; ++jl) {
                float v = acc[il][jl];
                #pragma unroll
                for (int msk = 1; msk < 64; msk <<= 1) v += __shfl_xor(v, msk, 64);
                acc[il][jl] = v;
            }
        float* wred = smem;              // overlay: 4*16 floats
        const int w = t >> 6;
        if ((t & 63) == 0) {
            #pragma unroll
            for (int il = 0; il < 4; ++il)
                #pragma unroll
                for (int jl = 0; jl < 4; ++jl) wred[w * 16 + il * 4 + jl] = acc[il][jl];
        }
        __syncthreads();
        if (t < 16) {
            const int il = t >> 2, jl = t & 3;
            const int i = i0 + il, j = j0 + jl;
            float v = wred[t] + wred[16 + t] + wred[32 + t] + wred[48 + t];
            edges[i * 64 + j] = (i == j) ? 1.0f : v;
        }
    } else if (blockIdx.x < 272) {
        // ---------------- out role ----------------
        const int mb = blockIdx.x - 256;      // 0..15
        const int kg = t >> 6;                // 4 kb-groups of 16 rows
        const int ml = t & 63;                // 64 float4 lanes
        const float* pp = part + (size_t)kg * 16 * FMAP + mb * 256 + ml * 4;
        float4 s = make_float4(0.f, 0.f, 0.f, 0.f);
        #pragma unroll
        for (int r = 0; r < 16; ++r) {
            const float4 v = *(const float4*)(pp + (size_t)r * FMAP);
            s.x += v.x; s.y += v.y; s.z += v.z; s.w += v.w;
        }
        float4* red4 = (float4*)smem;         // overlay: 4*64 float4 (4 KB)
        float*  rst  = smem + 2048;           // overlay: 256 floats
        red4[kg * 64 + ml] = s;
        __syncthreads();
        if (t < 64) {
            const float4 a = red4[t], b = red4[64 + t], c = red4[128 + t], d = red4[192 + t];
            const float4 bgv = *(const float4*)&bg[mb * 256 + t * 4];
            float4 r;
            r.x = a.x + b.x + c.x + d.x + bgv.x;
            r.y = a.y + b.y + c.y + d.y + bgv.y;
            r.z = a.z + b.z + c.z + d.z + bgv.z;
            r.w = a.w + b.w + c.w + d.w + bgv.w;
            *(float4*)&rst[t * 4] = r;
        }
        __syncthreads();
        const int row0 = t >> 6;    // 0..3
        const int c4   = t & 63;
        const float4 v = *(const float4*)&rst[c4 * 4];
        #pragma unroll
        for (int p = 0; p < 16; ++p) {
            const int n = p * 4 + row0;
            *(float4*)&out[(size_t)n * FMAP + mb * 256 + c4 * 4] = v;
        }
    }
}

extern "C" void kernel_launch(void* const* d_in, const int* in_sizes, int n_in,
                              void* d_out, int out_size, void* d_ws, size_t ws_size,
                              hipStream_t stream) {
    const float* x  = (const float*)d_in[0];   // (64,1,256,4,4)
    const float* We = (const float*)d_in[1];   // (256,512)
    const float* be = (const float*)d_in[2];   // (256,)
    const float* Wg = (const float*)d_in[3];   // (4096,4096)
    const float* bg = (const float*)d_in[4];   // (4096,)
    float* out   = (float*)d_out;
    float* edges = out + (size_t)NN * FMAP;

    unsigned* syncv = (unsigned*)d_ws;             // barrier counters (8 KB)
    float* fws  = (float*)((char*)d_ws + 8192);
    float* U    = fws;                             // 262144 floats (1 MB)
    float* Bm   = U + (size_t)NN * FMAP;           // 262144 floats (1 MB)
    float* part = Bm + (size_t)NN * FMAP;          // KCH*FMAP = 262144 floats (1 MB)

    hipMemsetAsync(syncv, 0, 8192, stream);        // zero counters each replay
    k_all<<<dim3(NBLK), 256, 0, stream>>>(x, We, be, Wg, bg,
                                          U, Bm, part, out, edges, syncv);
}

// Round 14
// 31.670 us; speedup vs baseline: 2.6498x; 1.1350x over previous
//
#include <hip/hip_runtime.h>
#include <hip/hip_bf16.h>

#define NN    64
#define CC    256
#define PP    16
#define FMAP  4096   // CC*PP
#define KCH   64     // k-chunks of 64 rows for the W_g matvec split
#define SIG   0x5EEDF00Du

// sync line layout (64B lines, dword index = line*16):
//  mvcnt[0..31]=L0-31  mvclaim[0..7]=L32-39  mvdone[0..7]=L40-47
//  MVGO=L48  MVREL=L49
//  ubcnt[0..31]=L50-81 ubclaim[0..7]=L82-89  ubdone[0..7]=L90-97
//  UBGO=L98  UBREL=L99
#define SL(l) ((l) * 16)

__device__ __forceinline__ unsigned ld(unsigned* p) {
    return __hip_atomic_load(p, __ATOMIC_RELAXED, __HIP_MEMORY_SCOPE_AGENT);
}
__device__ __forceinline__ void st(unsigned* p, unsigned v) {
    __hip_atomic_store(p, v, __ATOMIC_RELAXED, __HIP_MEMORY_SCOPE_AGENT);
}

// ---------------------------------------------------------------------------
// Single kernel, 512 blocks x 256 threads, NO global barrier:
//   blocks [0,256):  mv stream -> part; subset-sync -> flush -> MVREL.
//   blocks [256,512): ub GEMM -> U,Bm; subset-sync -> flush -> UBREL ->
//                     dist (all 256); dist ids [16,32) then spin MVREL -> out.
// All sync slots reset at kernel start by designated blocks (poison-safe).
// ---------------------------------------------------------------------------
__global__ __launch_bounds__(256) void k_all(const float* __restrict__ x,
                                             const float* __restrict__ We,
                                             const float* __restrict__ be,
                                             const float* __restrict__ Wg,
                                             const float* __restrict__ bg,
                                             float* __restrict__ U,
                                             float* __restrict__ Bm,
                                             float* __restrict__ part,
                                             float* __restrict__ out,
                                             float* __restrict__ edges,
                                             unsigned* __restrict__ sync) {
    __shared__ float smem[3 * 4096];
    const int t = threadIdx.x;

    if (blockIdx.x < 256) {
        // ======================= mv role =======================
        const int b = blockIdx.x;
        if (t == 0) {   // resets (used >=15us later)
            if (b < 32)              st(&sync[SL(b)], 0u);          // mvcnt
            else if (b < 40)         st(&sync[SL(32 + b - 32)], 0u);// mvclaim
            else if (b < 48)         st(&sync[SL(40 + b - 40)], 0u);// mvdone
            else if (b == 48)        st(&sync[SL(48)], 0u);         // MVGO
            else if (b == 49)        st(&sync[SL(49)], 0u);         // MVREL
        }
        const int qx = b & 3;
        const int kb = b >> 2;

        {
            const int kl = t & 63, q = t >> 6;
            float s = 0.f;
            #pragma unroll
            for (int nn = 0; nn < 16; ++nn)
                s += x[(size_t)(q * 16 + nn) * FMAP + kb * 64 + kl];
            smem[q * 64 + kl] = s;
        }
        __syncthreads();
        if (t < 64)
            smem[256 + t] = (smem[t] + smem[64 + t] + smem[128 + t] + smem[192 + t])
                            * (1.0f / 64.0f);
        __syncthreads();
        const float* aggs = smem + 256;

        const int m0 = qx * 1024 + t * 4;
        float4 acc = make_float4(0.f, 0.f, 0.f, 0.f);
        #pragma unroll 4
        for (int r4 = 0; r4 < 16; ++r4) {
            const float4 av = *(const float4*)&aggs[r4 * 4];
            const int k = kb * 64 + r4 * 4;
            const float4 w0 = *(const float4*)&Wg[(size_t)(k    ) * FMAP + m0];
            const float4 w1 = *(const float4*)&Wg[(size_t)(k + 1) * FMAP + m0];
            const float4 w2 = *(const float4*)&Wg[(size_t)(k + 2) * FMAP + m0];
            const float4 w3 = *(const float4*)&Wg[(size_t)(k + 3) * FMAP + m0];
            acc.x = fmaf(av.x, w0.x, acc.x); acc.y = fmaf(av.x, w0.y, acc.y);
            acc.z = fmaf(av.x, w0.z, acc.z); acc.w = fmaf(av.x, w0.w, acc.w);
            acc.x = fmaf(av.y, w1.x, acc.x); acc.y = fmaf(av.y, w1.y, acc.y);
            acc.z = fmaf(av.y, w1.z, acc.z); acc.w = fmaf(av.y, w1.w, acc.w);
            acc.x = fmaf(av.z, w2.x, acc.x); acc.y = fmaf(av.z, w2.y, acc.y);
            acc.z = fmaf(av.z, w2.z, acc.z); acc.w = fmaf(av.z, w2.w, acc.w);
            acc.x = fmaf(av.w, w3.x, acc.x); acc.y = fmaf(av.w, w3.y, acc.y);
            acc.z = fmaf(av.w, w3.z, acc.z); acc.w = fmaf(av.w, w3.w, acc.w);
        }
        *(float4*)&part[(size_t)kb * FMAP + m0] = acc;

        __syncthreads();     // drains vmcnt: part store in L2
        if (t == 0) {
            __hip_atomic_fetch_add(&sync[SL(b & 31)], 1u,
                                   __ATOMIC_RELAXED, __HIP_MEMORY_SCOPE_AGENT);
            unsigned xcd;
            asm volatile("s_getreg_b32 %0, hwreg(HW_REG_XCC_ID)" : "=s"(xcd));
            xcd &= 7;
            const bool won =
                (__hip_atomic_fetch_or(&sync[SL(32 + xcd)], 1u,
                                       __ATOMIC_RELAXED, __HIP_MEMORY_SCOPE_AGENT) == 0u);
            if (b == 0) {
                // root: wait all 256 arrived (32 lines x 8)
                for (;;) {
                    unsigned s = 0;
                    #pragma unroll
                    for (int i = 0; i < 32; ++i) s += ld(&sync[SL(i)]);
                    if (s == 256u) break;
                    __builtin_amdgcn_s_sleep(8);
                }
                st(&sync[SL(48)], SIG);              // MVGO
            }
            if (won) {
                while (ld(&sync[SL(48)]) != SIG) __builtin_amdgcn_s_sleep(8);
                asm volatile("buffer_wbl2 sc1\n\t"
                             "s_waitcnt vmcnt(0)" ::: "memory");
                st(&sync[SL(40 + xcd)], SIG);        // mvdone
            }
            if (b == 0) {
                for (;;) {
                    int ok = 1;
                    #pragma unroll
                    for (int i = 0; i < 8; ++i) ok &= (ld(&sync[SL(40 + i)]) == SIG);
                    if (ok) break;
                    __builtin_amdgcn_s_sleep(8);
                }
                st(&sync[SL(49)], SIG);              // MVREL
            }
        }
        return;
    }

    // ======================= ub role =======================
    const int g = blockIdx.x - 256;
    if (t == 0) {   // resets
        if (g < 32)              st(&sync[SL(50 + g)], 0u);         // ubcnt
        else if (g < 40)         st(&sync[SL(82 + g - 32)], 0u);    // ubclaim
        else if (g < 48)         st(&sync[SL(90 + g - 40)], 0u);    // ubdone
        else if (g == 48)        st(&sync[SL(98)], 0u);             // UBGO
        else if (g == 49)        st(&sync[SL(99)], 0u);             // UBREL
    }
    {
        const int o0   = (g & 7) * 32;
        const int col0 = (g >> 3) * 32;
        const int n0   = col0 >> 4;

        float* wts = smem;            // [kl][ol] : W1+W2
        float* wt2 = smem + 4096;     // [kl][ol] : W2
        float* xs  = smem + 8192;     // [kl][cl] : X

        const int kq  = t >> 6;
        const int pos = t & 63;
        const int og  = pos >> 3;
        const int cgi = pos & 7;
        const int wol = t >> 3, wseg = t & 7;

        float acc1[4][4] = {{0.f}}, acc2[4][4] = {{0.f}};

        for (int ch = 0; ch < 2; ++ch) {
            const int kb = ch * 128;
            if (ch) __syncthreads();

            {
                const float* wr = We + (size_t)(o0 + wol) * 512 + kb + wseg * 16;
                float w1v[16], w2v[16];
                #pragma unroll
                for (int q = 0; q < 16; q += 4) {
                    *(float4*)&w1v[q] = *(const float4*)(wr + q);
                    *(float4*)&w2v[q] = *(const float4*)(wr + 256 + q);
                }
                #pragma unroll
                for (int q = 0; q < 16; ++q) {
                    int kl = wseg * 16 + q;
                    wts[kl * 32 + wol] = w1v[q] + w2v[q];
                    wt2[kl * 32 + wol] = w2v[q];
                }
            }
            #pragma unroll
            for (int i = 0; i < 4; ++i) {
                int idx4 = t * 4 + i * 1024;
                int nl = idx4 >> 11, rem = idx4 & 2047;
                int kl = rem >> 4, p = rem & 15;
                float4 v = *(const float4*)&x[(size_t)(n0 + nl) * FMAP + (kb + kl) * PP + p];
                *(float4*)&xs[kl * 32 + nl * 16 + p] = v;
            }
            __syncthreads();

            const int kbase = kq * 32;
            #pragma unroll 8
            for (int kk = 0; kk < 32; ++kk) {
                int k = kbase + kk;
                const float4 a1 = *(const float4*)&wts[k * 32 + og * 4];
                const float4 a2 = *(const float4*)&wt2[k * 32 + og * 4];
                const float4 bx = *(const float4*)&xs [k * 32 + cgi * 4];
                const float av1[4] = {a1.x, a1.y, a1.z, a1.w};
                const float av2[4] = {a2.x, a2.y, a2.z, a2.w};
                const float bv [4] = {bx.x, bx.y, bx.z, bx.w};
                #pragma unroll
                for (int i2 = 0; i2 < 4; ++i2)
                    #pragma unroll
                    for (int j = 0; j < 4; ++j) {
                        acc1[i2][j] = fmaf(av1[i2], bv[j], acc1[i2][j]);
                        acc2[i2][j] = fmaf(av2[i2], bv[j], acc2[i2][j]);
                    }
            }
            __syncthreads();
        }

        float* red = smem;
        if (kq > 0) {
            float* dst = red + ((kq - 1) * 64 + pos) * 33;
            #pragma unroll
            for (int i2 = 0; i2 < 4; ++i2)
                #pragma unroll
                for (int j = 0; j < 4; ++j) {
                    dst[i2 * 4 + j]      = acc1[i2][j];
                    dst[16 + i2 * 4 + j] = acc2[i2][j];
                }
        }
        __syncthreads();
        if (kq == 0) {
            #pragma unroll
            for (int q = 0; q < 3; ++q) {
                const float* s = red + (q * 64 + pos) * 33;
                #pragma unroll
                for (int i2 = 0; i2 < 4; ++i2)
                    #pragma unroll
                    for (int j = 0; j < 4; ++j) {
                        acc1[i2][j] += s[i2 * 4 + j];
                        acc2[i2][j] += s[16 + i2 * 4 + j];
                    }
            }
            const int nl = cgi >> 2;
            const int p0 = (cgi * 4) & 15;
            const int n  = n0 + nl;
            #pragma unroll
            for (int i2 = 0; i2 < 4; ++i2) {
                const int o = o0 + og * 4 + i2;
                const float bias = be[o];
                const float4 xv = *(const float4*)&x[(size_t)n * FMAP + o * PP + p0];
                float4 uo, bo;
                uo.x = xv.x - acc1[i2][0] - bias;
                uo.y = xv.y - acc1[i2][1] - bias;
                uo.z = xv.z - acc1[i2][2] - bias;
                uo.w = xv.w - acc1[i2][3] - bias;
                bo.x = acc2[i2][0]; bo.y = acc2[i2][1];
                bo.z = acc2[i2][2]; bo.w = acc2[i2][3];
                *(float4*)&U [(size_t)n * FMAP + o * PP + p0] = uo;
                *(float4*)&Bm[(size_t)n * FMAP + o * PP + p0] = bo;
            }
        }
    }

    // -------- ub subset barrier + per-XCD flush + release --------
    __syncthreads();     // drains vmcnt: U/Bm stores in L2
    if (t == 0) {
        __hip_atomic_fetch_add(&sync[SL(50 + (g & 31))], 1u,
                               __ATOMIC_RELAXED, __HIP_MEMORY_SCOPE_AGENT);
        unsigned xcd;
        asm volatile("s_getreg_b32 %0, hwreg(HW_REG_XCC_ID)" : "=s"(xcd));
        xcd &= 7;
        const bool won =
            (__hip_atomic_fetch_or(&sync[SL(82 + xcd)], 1u,
                                   __ATOMIC_RELAXED, __HIP_MEMORY_SCOPE_AGENT) == 0u);
        if (g == 0) {
            for (;;) {
                unsigned s = 0;
                #pragma unroll
                for (int i = 0; i < 32; ++i) s += ld(&sync[SL(50 + i)]);
                if (s == 256u) break;
                __builtin_amdgcn_s_sleep(8);
            }
            st(&sync[SL(98)], SIG);                  // UBGO
        }
        if (won) {
            while (ld(&sync[SL(98)]) != SIG) __builtin_amdgcn_s_sleep(8);
            asm volatile("buffer_wbl2 sc1\n\t"
                         "s_waitcnt vmcnt(0)" ::: "memory");
            st(&sync[SL(90 + xcd)], SIG);            // ubdone
        }
        if (g == 0) {
            for (;;) {
                int ok = 1;
                #pragma unroll
                for (int i = 0; i < 8; ++i) ok &= (ld(&sync[SL(90 + i)]) == SIG);
                if (ok) break;
                __builtin_amdgcn_s_sleep(8);
            }
            st(&sync[SL(99)], SIG);                  // UBREL
        }
        while (ld(&sync[SL(99)]) != SIG) __builtin_amdgcn_s_sleep(8);
        asm volatile("" ::: "memory");
    }
    __syncthreads();

    // ======================= dist role =======================
    {
        const int i0 = (g >> 4) * 4;
        const int j0 = (g & 15) * 4;

        float acc[4][4] = {{0.f}};
        #pragma unroll
        for (int s = 0; s < 4; ++s) {
            const int m = s * 1024 + t * 4;
            float4 u[4], b4[4];
            #pragma unroll
            for (int jl = 0; jl < 4; ++jl) u[jl]  = *(const float4*)&U [(size_t)(j0 + jl) * FMAP + m];
            #pragma unroll
            for (int il = 0; il < 4; ++il) b4[il] = *(const float4*)&Bm[(size_t)(i0 + il) * FMAP + m];
            #pragma unroll
            for (int il = 0; il < 4; ++il)
                #pragma unroll
                for (int jl = 0; jl < 4; ++jl) {
                    acc[il][jl] += fabsf(u[jl].x - b4[il].x) + fabsf(u[jl].y - b4[il].y)
                                 + fabsf(u[jl].z - b4[il].z) + fabsf(u[jl].w - b4[il].w);
                }
        }
        #pragma unroll
        for (int il = 0; il < 4; ++il)
            #pragma unroll
            for (int jl = 0; jl < 4; ++jl) {
                float v = acc[il][jl];
                #pragma unroll
                for (int msk = 1; msk < 64; msk <<= 1) v += __shfl_xor(v, msk, 64);
                acc[il][jl] = v;
            }
        float* wred = smem;
        const int w = t >> 6;
        if ((t & 63) == 0) {
            #pragma unroll
            for (int il = 0; il < 4; ++il)
                #pragma unroll
                for (int jl = 0; jl < 4; ++jl) wred[w * 16 + il * 4 + jl] = acc[il][jl];
        }
        __syncthreads();
        if (t < 16) {
            const int il = t >> 2, jl = t & 3;
            const int i = i0 + il, j = j0 + jl;
            float v = wred[t] + wred[16 + t] + wred[32 + t] + wred[48 + t];
            edges[i * 64 + j] = (i == j) ? 1.0f : v;
        }
    }

    // ======================= out role (dist ids 16..31) =======================
    if (g >= 16 && g < 32) {
        __syncthreads();
        if (t == 0) {
            while (ld(&sync[SL(49)]) != SIG) __builtin_amdgcn_s_sleep(8);   // MVREL
            asm volatile("" ::: "memory");
        }
        __syncthreads();
        const int mb = g - 16;                // 0..15
        const int kg = t >> 6;                // 4 kb-groups of 16 rows
        const int ml = t & 63;                // 64 float4 lanes
        const float* pp = part + (size_t)kg * 16 * FMAP + mb * 256 + ml * 4;
        float4 s = make_float4(0.f, 0.f, 0.f, 0.f);
        #pragma unroll
        for (int r = 0; r < 16; ++r) {
            const float4 v = *(const float4*)(pp + (size_t)r * FMAP);
            s.x += v.x; s.y += v.y; s.z += v.z; s.w += v.w;
        }
        float4* red4 = (float4*)smem;
        float*  rst  = smem + 2048;
        __syncthreads();
        red4[kg * 64 + ml] = s;
        __syncthreads();
        if (t < 64) {
            const float4 a = red4[t], b4 = red4[64 + t], c = red4[128 + t], d = red4[192 + t];
            const float4 bgv = *(const float4*)&bg[mb * 256 + t * 4];
            float4 r;
            r.x = a.x + b4.x + c.x + d.x + bgv.x;
            r.y = a.y + b4.y + c.y + d.y + bgv.y;
            r.z = a.z + b4.z + c.z + d.z + bgv.z;
            r.w = a.w + b4.w + c.w + d.w + bgv.w;
            *(float4*)&rst[t * 4] = r;
        }
        __syncthreads();
        const int row0 = t >> 6;
        const int c4   = t & 63;
        const float4 v = *(const float4*)&rst[c4 * 4];
        #pragma unroll
        for (int p = 0; p < 16; ++p) {
            const int n = p * 4 + row0;
            *(float4*)&out[(size_t)n * FMAP + mb * 256 + c4 * 4] = v;
        }
    }
}

extern "C" void kernel_launch(void* const* d_in, const int* in_sizes, int n_in,
                              void* d_out, int out_size, void* d_ws, size_t ws_size,
                              hipStream_t stream) {
    const float* x  = (const float*)d_in[0];   // (64,1,256,4,4)
    const float* We = (const float*)d_in[1];   // (256,512)
    const float* be = (const float*)d_in[2];   // (256,)
    const float* Wg = (const float*)d_in[3];   // (4096,4096)
    const float* bg = (const float*)d_in[4];   // (4096,)
    float* out   = (float*)d_out;
    float* edges = out + (size_t)NN * FMAP;

    unsigned* syncv = (unsigned*)d_ws;             // 100 lines = 6.4 KB (self-resetting)
    float* fws  = (float*)((char*)d_ws + 8192);
    float* U    = fws;                             // 262144 floats (1 MB)
    float* Bm   = U + (size_t)NN * FMAP;           // 262144 floats (1 MB)
    float* part = Bm + (size_t)NN * FMAP;          // KCH*FMAP = 262144 floats (1 MB)

    k_all<<<dim3(512), 256, 0, stream>>>(x, We, be, Wg, bg,
                                         U, Bm, part, out, edges, syncv);
}